// Round 1
// baseline (131.618 us; speedup 1.0000x reference)
//
#include <hip/hip_runtime.h>
#include <hip/hip_bf16.h>
#include <math.h>

#define BB 4
#define CC 192
#define HH 56
#define WW 56
#define HWW 3136

typedef __attribute__((ext_vector_type(8))) short short8;
typedef __attribute__((ext_vector_type(4))) float f32x4;

__device__ __forceinline__ unsigned short f2b(float f) {
    __hip_bfloat16 h = __float2bfloat16(f);
    return __builtin_bit_cast(unsigned short, h);
}
__device__ __forceinline__ float b2f(unsigned short u) {
    unsigned int x = ((unsigned int)u) << 16;
    return __builtin_bit_cast(float, x);
}

// ---------------------------------------------------------------------------
// Kernel 1: blocks [0,2352): transpose x (B,C,H,W) -> xt (B,HW,C) f32
//           blocks [2352,2640): W' = [C1;C2] -> split bf16 (N=384, K=192)
// ---------------------------------------------------------------------------
__global__ __launch_bounds__(256) void k_pre(const float* __restrict__ x,
                                             const float* __restrict__ cw,
                                             float* __restrict__ xt,
                                             unsigned short* __restrict__ cwh,
                                             unsigned short* __restrict__ cwl) {
    int tid = threadIdx.x, bid = blockIdx.x;
    if (bid < 2352) {
        __shared__ float tile[32][33];
        int b = bid / 588, rem = bid % 588;
        int by = rem / 98, bx = rem % 98;
        int tx = tid & 31, ty = tid >> 5;
        int p0 = bx * 32, c0 = by * 32;
#pragma unroll
        for (int i = 0; i < 4; i++) {
            int c = c0 + ty + 8 * i;
            tile[ty + 8 * i][tx] = x[(b * CC + c) * HWW + p0 + tx];
        }
        __syncthreads();
#pragma unroll
        for (int i = 0; i < 4; i++) {
            int p = p0 + ty + 8 * i;
            xt[(size_t)(b * HWW + p) * CC + c0 + tx] = tile[tx][ty + 8 * i];
        }
    } else {
        int i = (bid - 2352) * 256 + tid;
        if (i < 384 * 192) {
            int n = i / 192, k = i % 192;
            float v = (n < 192) ? cw[n * 384 + k] : cw[(n - 192) * 384 + 192 + k];
            unsigned short hi = f2b(v);
            cwh[i] = hi;
            cwl[i] = f2b(v - b2f(hi));
        }
    }
}

// ---------------------------------------------------------------------------
// Kernel 2 (fused independent work, reads xt/cwh/cwl only):
//   blocks [0,1792):    scores (pair symmetry) -> sp [half][b][pix][32]
//   blocks [1792,2968): GEMM [u|z] = W'·x^T, M=12544, N=384, K=192, split-bf16
// ---------------------------------------------------------------------------
__global__ __launch_bounds__(256) void k_mid(const float* __restrict__ xt,
                                             const unsigned short* __restrict__ cwh,
                                             const unsigned short* __restrict__ cwl,
                                             float* __restrict__ sp,
                                             float* __restrict__ u,
                                             float* __restrict__ z) {
    __shared__ __align__(16) char smem[36864];
    int tid = threadIdx.x, bid = blockIdx.x;

    if (bid < 1792) {                 // ---------------- scores ----------------
        float* Xs = (float*)smem;     // 28 rows x 96ch (+4 pad)
        const float K2 = 0.38490017945975050f;  // 2/sqrt(27)
        bool isH = bid < 896;
        int lid = isH ? bid : bid - 896;
        int half = lid & 1;
        int rp = (lid >> 1) & 1;
        int cb2 = lid >> 2;
        int b = cb2 / 56, l0 = cb2 % 56;
        int r0 = rp * 2;

        const float* src = xt + (size_t)(b * HWW) * CC + half * 96;
        for (int idx = tid; idx < 28 * 24; idx += 256) {
            int t2 = idx / 24, cq = idx % 24;
            int pi = (r0 + t2 / 14) + 4 * (t2 % 14);
            int pix = isH ? (pi * WW + l0) : (l0 * WW + pi);
            float4 v = *(const float4*)(src + (size_t)pix * CC + cq * 4);
            *(float4*)&Xs[t2 * 100 + cq * 4] = v;
        }
        __syncthreads();

        int perCls = isH ? 105 : 91;
        if (tid < 2 * perCls) {
            int cls = tid / perCls, p = tid % perCls;
            int a, bb;
            if (isH) {
                a = (int)((sqrtf((float)(8 * p + 1)) - 1.0f) * 0.5f);
                bb = p - (a * (a + 1)) / 2;
            } else {
                int ap = (int)((sqrtf((float)(8 * p + 1)) - 1.0f) * 0.5f);
                bb = p - (ap * (ap + 1)) / 2;
                a = ap + 1;
            }
            const float* pA = &Xs[(cls * 14 + a) * 100];
            const float* pB = &Xs[(cls * 14 + bb) * 100];
            float s0 = 0.f, s1 = 0.f, s2 = 0.f, s3 = 0.f;
#pragma unroll
            for (int q = 0; q < 24; q++) {
                float4 av = *(const float4*)(pA + q * 4);
                float4 bv = *(const float4*)(pB + q * 4);
                s0 += __builtin_amdgcn_rcpf(__expf(av.x * bv.x * K2) + 1.0f);
                s1 += __builtin_amdgcn_rcpf(__expf(av.y * bv.y * K2) + 1.0f);
                s2 += __builtin_amdgcn_rcpf(__expf(av.z * bv.z * K2) + 1.0f);
                s3 += __builtin_amdgcn_rcpf(__expf(av.w * bv.w * K2) + 1.0f);
            }
            float s = 96.0f - 2.0f * (s0 + s1 + s2 + s3);   // sum_c tanh
            int r = r0 + cls;
            size_t base = (size_t)(half * BB + b) * HWW;
            if (isH) {
                int i1 = a - bb;
                int h1 = r + 4 * a, h2 = r + 4 * bb;
                sp[(base + h1 * WW + l0) * 32 + i1] = s;
                if (a != bb) sp[(base + h2 * WW + l0) * 32 + (14 - i1)] = s;
            } else {
                int d = a - bb;                        // 1..13
                int w1 = r + 4 * a, w2 = r + 4 * bb;
                sp[(base + l0 * WW + w1) * 32 + 14 + (d - 1)] = s;
                sp[(base + l0 * WW + w2) * 32 + 14 + (13 - d)] = s;
            }
        }
        return;
    }

    // ---------------- GEMM [u|z], split-bf16, tile 64x64, K=192 ----------------
    {
        unsigned short* Ah = (unsigned short*)smem;
        unsigned short* Al = Ah + 64 * 72;
        unsigned short* Bh = Ah + 2 * 64 * 72;
        unsigned short* Bl = Ah + 3 * 64 * 72;
        float* Ds = (float*)smem;
        int vb = bid - 1792;                  // 0..1175
        int bm = (vb % 196) * 64, bn = (vb / 196) * 64;
        int lane = tid & 63, wv = tid >> 6;

        f32x4 acc[4] = {{0,0,0,0},{0,0,0,0},{0,0,0,0},{0,0,0,0}};

        for (int kc = 0; kc < 3; kc++) {
#pragma unroll
            for (int r2 = 0; r2 < 2; r2++) {
                int idx = tid + r2 * 256;
                int m = idx >> 3, kq = idx & 7;
                const float* s = xt + (size_t)(bm + m) * CC + kc * 64 + kq * 8;
                float4 v0 = *(const float4*)s;
                float4 v1 = *(const float4*)(s + 4);
                float vv[8] = {v0.x, v0.y, v0.z, v0.w, v1.x, v1.y, v1.z, v1.w};
                unsigned short hi[8], lo[8];
#pragma unroll
                for (int e = 0; e < 8; e++) {
                    hi[e] = f2b(vv[e]);
                    lo[e] = f2b(vv[e] - b2f(hi[e]));
                }
                *(short8*)&Ah[m * 72 + kq * 8] = *(short8*)hi;
                *(short8*)&Al[m * 72 + kq * 8] = *(short8*)lo;
                size_t bo = (size_t)(bn + m) * 192 + kc * 64 + kq * 8;
                *(short8*)&Bh[m * 72 + kq * 8] = *(const short8*)(cwh + bo);
                *(short8*)&Bl[m * 72 + kq * 8] = *(const short8*)(cwl + bo);
            }
            __syncthreads();
            int n0 = wv * 16;
            int k8 = lane >> 4;
            int col = lane & 15;
#pragma unroll
            for (int ks = 0; ks < 64; ks += 32) {
                int koff = ks + k8 * 8;
                short8 bfh = *(const short8*)&Bh[(n0 + col) * 72 + koff];
                short8 bfl = *(const short8*)&Bl[(n0 + col) * 72 + koff];
#pragma unroll
                for (int fm = 0; fm < 4; fm++) {
                    short8 afh = *(const short8*)&Ah[(fm * 16 + col) * 72 + koff];
                    short8 afl = *(const short8*)&Al[(fm * 16 + col) * 72 + koff];
                    acc[fm] = __builtin_amdgcn_mfma_f32_16x16x32_bf16(afh, bfh, acc[fm], 0, 0, 0);
                    acc[fm] = __builtin_amdgcn_mfma_f32_16x16x32_bf16(afl, bfh, acc[fm], 0, 0, 0);
                    acc[fm] = __builtin_amdgcn_mfma_f32_16x16x32_bf16(afh, bfl, acc[fm], 0, 0, 0);
                }
            }
            __syncthreads();
        }
        // LDS transpose: Ds[m][n], stride 68
        {
            int col = lane & 15, rowq = lane >> 4;
#pragma unroll
            for (int fm = 0; fm < 4; fm++)
#pragma unroll
                for (int rg = 0; rg < 4; rg++)
                    Ds[(fm * 16 + rowq * 4 + rg) * 68 + wv * 16 + col] = acc[fm][rg];
        }
        __syncthreads();
        // Store pixel-major: u (n<192) or z (n>=192)
        {
            int c4 = tid & 15, m0 = tid >> 4;
            int cg = bn + c4 * 4;
            float* dst = (cg < 192) ? u : z;
            int cc = (cg < 192) ? cg : cg - 192;
#pragma unroll
            for (int p = 0; p < 4; p++) {
                int m = m0 + p * 16;
                float4 v = *(float4*)&Ds[m * 68 + c4 * 4];
                *(float4*)&dst[(size_t)(bm + m) * CC + cc] = v;
            }
        }
    }
}

// ---------------------------------------------------------------------------
// Kernel 3: per-pixel softmax over 27 scores -> wn[b*HW + pix][28]  (slot 27 = 0)
// 49 blocks x 256 threads = 12544 pixels exactly.
// ---------------------------------------------------------------------------
__global__ __launch_bounds__(256) void k_soft(const float* __restrict__ sp,
                                              float* __restrict__ wn) {
    int gp = blockIdx.x * 256 + threadIdx.x;           // b*3136 + pix
    const float4* p0 = (const float4*)&sp[(size_t)gp * 32];
    const float4* p1 = (const float4*)&sp[((size_t)(4 * HWW) + gp) * 32];
    float sc[28];
#pragma unroll
    for (int j = 0; j < 7; j++) {
        float4 a = p0[j], v = p1[j];
        sc[4 * j + 0] = a.x + v.x; sc[4 * j + 1] = a.y + v.y;
        sc[4 * j + 2] = a.z + v.z; sc[4 * j + 3] = a.w + v.w;
    }
    float mx = -1e30f;
#pragma unroll
    for (int s = 0; s < 27; s++) mx = fmaxf(mx, sc[s]);
    float sum = 0.f;
#pragma unroll
    for (int s = 0; s < 27; s++) { sc[s] = __expf(sc[s] - mx); sum += sc[s]; }
    float inv = __builtin_amdgcn_rcpf(sum);
#pragma unroll
    for (int s = 0; s < 27; s++) sc[s] *= inv;
    sc[27] = 0.f;
    float4* dst = (float4*)(wn + (size_t)gp * 28);
#pragma unroll
    for (int j = 0; j < 7; j++)
        dst[j] = make_float4(sc[4 * j], sc[4 * j + 1], sc[4 * j + 2], sc[4 * j + 3]);
}

// ---------------------------------------------------------------------------
// Kernel 4: fused H+W accumulation + bias + BN + GELU.
// Block = (b, r-phase, 8-ch chunk, t-half): stages z rows ≡ r (mod 4) for its
// 8 channels into LDS (25 KB), H-conv from registers, W-conv from LDS.
// Grid 768 = 4b x 4r x 24cc x 2th, 448 threads (w fast over 8ch: tid = w*8+c).
// ---------------------------------------------------------------------------
__global__ __launch_bounds__(448) void k_accHW(const float* __restrict__ u,
                                               const float* __restrict__ z,
                                               const float* __restrict__ wn,
                                               const float* __restrict__ cb,
                                               const float* __restrict__ gma,
                                               const float* __restrict__ bta,
                                               const float* __restrict__ mea,
                                               const float* __restrict__ var,
                                               float* __restrict__ y) {
    __shared__ float Zs[14 * 56 * 8];     // [t][w][c], c fastest -> conflict-free
    int tid = threadIdx.x, bid = blockIdx.x;
    int th = bid & 1;
    int t1 = bid >> 1;                    // 0..383
    int cc = t1 % 24;
    int t2 = t1 / 24;                     // 0..15
    int r = t2 & 3;
    int b = t2 >> 2;
    int w = tid >> 3, c = tid & 7;
    int cg = cc * 8 + c;

    // stage z slab: rows r, r+4, ..., r+52; all 56 w; channels [cc*8, cc*8+8)
#pragma unroll
    for (int it = 0; it < 2; it++) {
        int idx = tid + it * 448;
        if (idx < 784) {
            int t = idx / 56, ww = idx - t * 56;
            const float* s = z + ((size_t)(b * HWW + (r + 4 * t) * WW + ww)) * CC + cc * 8;
            float4 v0 = *(const float4*)s;
            float4 v1 = *(const float4*)(s + 4);
            float* d = &Zs[(t * 56 + ww) * 8];
            *(float4*)d = v0;
            *(float4*)(d + 4) = v1;
        }
    }
    __syncthreads();

    // this thread's z column, pre-rotated by th*7 so all reg indices are static
    float zc[14];
#pragma unroll
    for (int m = 0; m < 14; m++) {
        int t0 = m + th * 7;
        if (t0 >= 14) t0 -= 14;
        zc[m] = Zs[(t0 * 56 + w) * 8 + c];
    }

    float bias = cb[cg];
    float ginv = gma[cg] * rsqrtf(var[cg] + 1e-5f);
    float bt = bta[cg];
    float me = mea[cg];

    int hbase = r + 4 * (th * 7);
    float acc[7];
#pragma unroll
    for (int tt = 0; tt < 7; tt++) {
        int pix = (hbase + 4 * tt) * WW + w;
        acc[tt] = u[((size_t)(b * HWW + pix)) * CC + cg];
    }

#pragma unroll
    for (int tt = 0; tt < 7; tt++) {
        int t = th * 7 + tt;
        int pix = (hbase + 4 * tt) * WW + w;
        size_t gp = (size_t)b * HWW + pix;
        const float4* wp = (const float4*)(wn + gp * 28);
        float wt[28];
        *(float4*)&wt[0]  = wp[0];
        *(float4*)&wt[4]  = wp[1];
        *(float4*)&wt[8]  = wp[2];
        *(float4*)&wt[12] = wp[3];
        *(float4*)&wt[16] = wp[4];
        *(float4*)&wt[20] = wp[5];
        *(float4*)&wt[24] = wp[6];
        float a = acc[tt];
        // H-part: shift 4i along rows; zc is rotated so (tt-i) index is static
#pragma unroll
        for (int i = 0; i < 14; i++)
            a += wt[i] * zc[(tt - i + 14) % 14];
        // W-part: shift 4j along cols, from LDS
#pragma unroll
        for (int j = 1; j <= 13; j++) {
            int wj = w - 4 * j;
            if (wj < 0) wj += 56;
            a += wt[13 + j] * Zs[(t * 56 + wj) * 8 + c];
        }
        float v = (a + bias - me) * ginv + bt;
        v = 0.5f * v * (1.0f + erff(v * 0.70710678118654752f));
        y[((size_t)(b * CC + cg)) * HWW + pix] = v;
    }
}

// ---------------------------------------------------------------------------
extern "C" void kernel_launch(void* const* d_in, const int* in_sizes, int n_in,
                              void* d_out, int out_size, void* d_ws, size_t ws_size,
                              hipStream_t stream) {
    const float* x   = (const float*)d_in[0];
    const float* cw  = (const float*)d_in[1];
    const float* cb  = (const float*)d_in[2];
    const float* gma = (const float*)d_in[3];
    const float* bta = (const float*)d_in[4];
    const float* mea = (const float*)d_in[5];
    const float* var = (const float*)d_in[6];
    float* out = (float*)d_out;

    float* ws = (float*)d_ws;
    float*          xt  = ws;                                   // 2,408,448
    float*          sp  = ws + 2408448;                         //   802,816
    float*          u   = ws + 3211264;                         // 2,408,448
    float*          z   = ws + 5619712;                         // 2,408,448
    float*          wn  = ws + 8028160;                         //   351,232
    unsigned short* cwh = (unsigned short*)(ws + 10436608);     //    73,728 us
    unsigned short* cwl = (unsigned short*)(ws + 10473472);

    k_pre<<<2640, 256, 0, stream>>>(x, cw, xt, cwh, cwl);
    k_mid<<<2968, 256, 0, stream>>>(xt, cwh, cwl, sp, u, z);
    k_soft<<<49, 256, 0, stream>>>(sp, wn);
    k_accHW<<<768, 448, 0, stream>>>(u, z, wn, cb, gma, bta, mea, var, out);
}